// Round 12
// baseline (57.346 us; speedup 1.0000x reference)
//
#include <hip/hip_runtime.h>
#include <hip/hip_bf16.h>
#include <cstdint>
#include <cstddef>

// Problem dims (fixed by the reference: B=4, C=256, H=W=64)
#define C_    256
#define C8_   32
#define NPIX  4096
#define BATCH 4
#define OUT_ELEMS (BATCH * C_ * NPIX)   // out [4,256,64,64]; then attention [4096][4096]

typedef short bf16x8 __attribute__((ext_vector_type(8)));   // 8 bf16 in 4 VGPRs
typedef float f32x4  __attribute__((ext_vector_type(4)));
typedef unsigned uint32x2 __attribute__((ext_vector_type(2)));

#define LOG2E 1.44269504088896340736f

// k_attn5 LDS p-staging: per wave [16 rows][264 bf16] (HALF a j-range of 512;
// 256 data + 8 pad). 8*16*264*2B = 67.6 KB -> 2 blocks/CU.
#define PROW 264

static __device__ __forceinline__ unsigned short f2bf(float f) {
    union { float f; unsigned u; } v; v.f = f;
    unsigned r = v.u + 0x7fff + ((v.u >> 16) & 1);   // RNE
    return (unsigned short)(r >> 16);
}

// pack two f32 -> two bf16 (TRUNCATE) in one v_perm: low half = p0, high = p1
static __device__ __forceinline__ unsigned pack_bf2(float p0, float p1) {
    union { float f; unsigned u; } a, b; a.f = p0; b.f = p1;
    return __builtin_amdgcn_perm(b.u, a.u, 0x07060302u);
}
static __device__ __forceinline__ float unpk_lo(unsigned u) {
    union { unsigned u; float f; } v; v.u = u << 16; return v.f;
}
static __device__ __forceinline__ float unpk_hi(unsigned u) {
    union { unsigned u; float f; } v; v.u = u & 0xffff0000u; return v.f;
}

static __device__ __forceinline__ f32x4 mfma16(bf16x8 a, bf16x8 b, f32x4 c) {
    return __builtin_amdgcn_mfma_f32_16x16x32_bf16(a, b, c, 0, 0, 0);
}

// ---------------------------------------------------------------------------
// K1 "k_proj": [0,2048)    q/k projection (LDS-staged x, s_load W; R9-proven)
//              [2048,6144) v projection (skipped when gamma==0)
// gamma==0: only the 512 b==0 qk blocks do work; rest early-return.
//   qT,kT: bf16 [B][N][32] (c contiguous). q PRESCALED by log2(e).
//   vB   : bf16 [B][C][N]
// ---------------------------------------------------------------------------
__global__ __launch_bounds__(256) void k_proj(
    const float* __restrict__ x,
    const float* __restrict__ Wq, const float* __restrict__ bq,
    const float* __restrict__ Wk, const float* __restrict__ bk,
    const float* __restrict__ Wv, const float* __restrict__ bv,
    const float* __restrict__ gamma,
    unsigned short* __restrict__ qT,
    unsigned short* __restrict__ kT,
    unsigned short* __restrict__ vB)
{
    __shared__ float xs[256][64];     // 64 KB x-tile (qk role)
    __shared__ float pred[4][8][64];  // 8 KB cross-wave partials (qk role)

    const int bid = blockIdx.x;
    const float gval = gamma[0];

    if (bid < 2048) {                       // ---- q/k projection role ----
        const int idx = bid;
        const int b   = idx >> 9;           // 512 blocks per batch
        if (gval == 0.0f && b > 0) return;  // attention only observed at b==0
        const int sub  = idx & 511;
        const int og8  = sub >> 6;          // 0..7: 0-3 = q, 4-7 = k (uniform)
        const int n0   = (sub & 63) * 64;
        const bool is_q = (og8 < 4);
        const int obase = (og8 & 3) * 8;    // 8 outputs per block

        // stage x-tile [256 c][64 n]: 16 independent f32x4 loads per thread
        const int tl = threadIdx.x & 15;    // col group (4 floats)
        const int tr = threadIdx.x >> 4;    // row within pass (0..15)
        const float* xb = x + (size_t)b * C_ * NPIX + n0;
        f32x4 v[16];
#pragma unroll
        for (int p = 0; p < 16; ++p)
            v[p] = *(const f32x4*)(xb + (size_t)(p * 16 + tr) * NPIX + tl * 4);
#pragma unroll
        for (int p = 0; p < 16; ++p)
            *(f32x4*)&xs[p * 16 + tr][tl * 4] = v[p];
        __syncthreads();

        // each wave reduces its c-chunk of 64 for 8 outputs x 64 pixels
        const int wv = __builtin_amdgcn_readfirstlane(threadIdx.x >> 6); // 0..3
        const int ln = threadIdx.x & 63;    // pixel
        const float* Wb = (is_q ? Wq : Wk); // uniform (blockIdx-derived)
        float acc[8] = {0.f, 0.f, 0.f, 0.f, 0.f, 0.f, 0.f, 0.f};
#pragma unroll 8
        for (int cc = 0; cc < 64; ++cc) {
            const int c = wv * 64 + cc;     // wave-uniform -> W via s_load
            const float xv = xs[c][ln];
#pragma unroll
            for (int o = 0; o < 8; ++o)
                acc[o] = fmaf(Wb[(size_t)(obase + o) * C_ + c], xv, acc[o]);
        }
#pragma unroll
        for (int o = 0; o < 8; ++o) pred[wv][o][ln] = acc[o];
        __syncthreads();

        // reduce 4 partials + bias, convert, store (thread t -> 2 outputs)
        const int o1 = threadIdx.x >> 6;    // 0..3
        const int n  = threadIdx.x & 63;
#pragma unroll
        for (int k = 0; k < 2; ++k) {
            const int ol = o1 + k * 4;
            const int oa = obase + ol;
            float s = pred[0][ol][n] + pred[1][ol][n] +
                      pred[2][ol][n] + pred[3][ol][n];
            if (is_q) {
                s = (s + bq[oa]) * LOG2E;
                qT[((size_t)b * NPIX + n0 + n) * C8_ + oa] = f2bf(s);
            } else {
                s = s + bk[oa];
                kT[((size_t)b * NPIX + n0 + n) * C8_ + oa] = f2bf(s);
            }
        }
        return;
    }

    {                                       // ---- v projection role ----
        if (gval == 0.0f) return;
        const int idx = bid - 2048;
        const int b   = idx >> 10;          // 1024 blocks per batch
        const int rem = idx & 1023;
        const int w   = threadIdx.x >> 6;
        const int o0  = ((rem >> 6) * 4 + w) * 4;
        const int n   = (rem & 63) * 64 + (threadIdx.x & 63);

        float acc[4];
#pragma unroll
        for (int m = 0; m < 4; ++m) acc[m] = bv[o0 + m];
        const float* xb = x + (size_t)b * C_ * NPIX + n;
#pragma unroll 4
        for (int c = 0; c < C_; ++c) {
            float xv = xb[(size_t)c * NPIX];
#pragma unroll
            for (int m = 0; m < 4; ++m) acc[m] = fmaf(Wv[(o0 + m) * C_ + c], xv, acc[m]);
        }
#pragma unroll
        for (int m = 0; m < 4; ++m)
            vB[((size_t)b * C_ + o0 + m) * NPIX + n] = f2bf(acc[m]);
    }
}

// ---------------------------------------------------------------------------
// K2 "k_attn5": flat grid 1024, roles INTERLEAVED so attention blocks spread
// across all CUs regardless of dispatch packing (R11 theory #2):
//  gamma==0: fid&3==0 -> attention (b=0, i-tile fid>>2);
//            else     -> out=x copy slice (768 blocks, overlaps attention).
//  gamma!=0: all 1024 -> attention (b = fid&3, i-tile fid>>2) + PV + epilogue.
// All stores are PLAIN (not nontemporal): harness fills prove plain stores
// stream at 6.5-6.9 TB/s; nt was never A/B'd and is suspect (R11 theory #1).
// Two j-halves per wave staged via 68 KB pbuf as in R11.
// Lane layout (m89-verified D): j = jw + s*16 + lg*4 + r, i = i0 + li.
// ---------------------------------------------------------------------------
__global__ __launch_bounds__(512) void k_attn5(
    const float* __restrict__ x,
    const unsigned short* __restrict__ qT,
    const unsigned short* __restrict__ kT,
    const unsigned short* __restrict__ vB,
    const float* __restrict__ gamma,
    float* __restrict__ out,
    float* __restrict__ attn)
{
    const int fid = blockIdx.x;
    const float g = gamma[0];

    __shared__ unsigned short pbuf[8 * 16 * PROW];   // 67.6 KB half-staging
    __shared__ float red[8][16];

    int b, it;
    if (g == 0.0f) {
        if ((fid & 3) != 0) {               // ---- copy role (768 blocks) ----
            const int cb = (fid >> 2) * 3 + (fid & 3) - 1;   // 0..767
            const size_t n4 = (size_t)OUT_ELEMS / 4;         // 1,048,576 f32x4
            const f32x4* src = (const f32x4*)x;
            f32x4* dst = (f32x4*)out;
            for (size_t i = (size_t)cb * 512 + threadIdx.x; i < n4;
                 i += (size_t)768 * 512)
                dst[i] = src[i];
            return;
        }
        b = 0; it = fid >> 2;
    } else {
        b = fid & 3; it = fid >> 2;
    }

    const int i0   = it * 16;
    const int t    = threadIdx.x;
    const int lane = t & 63;
    const int wavei = __builtin_amdgcn_readfirstlane(t >> 6);  // 0..7
    const int li   = lane & 15;
    const int lg   = lane >> 4;       // 0..3

    const unsigned short* qTb = qT + (size_t)b * NPIX * C8_;
    const unsigned short* kTb = kT + (size_t)b * NPIX * C8_;

    // B fragment (Q, prescaled by log2e): rows i0+li, k-elems lg*8..+7
    bf16x8 qf = *(const bf16x8*)(qTb + (size_t)(i0 + li) * C8_ + lg * 8);

    const int jw = wavei * 512;
    unsigned short* prow = pbuf + (size_t)(wavei * 16 + li) * PROW;

    float ssum = 0.f;
    // HALF 0 (j local [0,256)): energy -> exp2 -> packed bf16 into pbuf
#pragma unroll
    for (int s = 0; s < 16; ++s) {
        bf16x8 kf = *(const bf16x8*)(kTb + (size_t)(jw + s * 16 + li) * C8_ + lg * 8);
        f32x4 z = {0.f, 0.f, 0.f, 0.f};
        f32x4 e = mfma16(kf, qf, z);           // e = S * log2e
        float p0 = exp2f(e[0]), p1 = exp2f(e[1]);
        float p2 = exp2f(e[2]), p3 = exp2f(e[3]);
        ssum += (p0 + p1) + (p2 + p3);
        uint32x2 pk;
        pk.x = pack_bf2(p0, p1);
        pk.y = pack_bf2(p2, p3);
        *(uint32x2*)(prow + s * 16 + lg * 4) = pk;   // 8B ds_write_b64
    }
    // HALF 1 (j local [256,512)): keep packed in registers (32 VGPR)
    uint32x2 sp2[16];
#pragma unroll
    for (int s = 0; s < 16; ++s) {
        bf16x8 kf = *(const bf16x8*)(kTb + (size_t)(jw + 256 + s * 16 + li) * C8_ + lg * 8);
        f32x4 z = {0.f, 0.f, 0.f, 0.f};
        f32x4 e = mfma16(kf, qf, z);
        float p0 = exp2f(e[0]), p1 = exp2f(e[1]);
        float p2 = exp2f(e[2]), p3 = exp2f(e[3]);
        ssum += (p0 + p1) + (p2 + p3);
        sp2[s].x = pack_bf2(p0, p1);
        sp2[s].y = pack_bf2(p2, p3);
    }

    // row sum: in-wave (across lg) then cross-wave via LDS
    ssum += __shfl_xor(ssum, 16, 64);
    ssum += __shfl_xor(ssum, 32, 64);
    if (lane < 16) red[wavei][lane] = ssum;
    __syncthreads();                   // pbuf half0 also visible block-wide
    float l = 0.f;
#pragma unroll
    for (int w = 0; w < 8; ++w) l += red[w][li];
    const float inv = 1.0f / l;        // row i0+li (lanes 0..15 canonical)

    const bool do_pv = (g != 0.0f);
    f32x4 o0 = {0.f, 0.f, 0.f, 0.f};
    f32x4 o1 = {0.f, 0.f, 0.f, 0.f};
    const unsigned short* vb = vB + (size_t)b * C_ * NPIX;

    // ---- HALF 0: attn stores (b==0) + PV (gamma!=0) ----
    if (b == 0) {
#pragma unroll
        for (int r = 0; r < 16; ++r) {
            const float inv_r = __shfl(inv, r, 64);
            const unsigned short* rp = pbuf + (size_t)(wavei * 16 + r) * PROW;
            uint32x2 u = *(const uint32x2*)(rp + lane * 4);   // 8B ds_read_b64
            f32x4 v4;
            v4[0] = unpk_lo(u.x) * inv_r; v4[1] = unpk_hi(u.x) * inv_r;
            v4[2] = unpk_lo(u.y) * inv_r; v4[3] = unpk_hi(u.y) * inv_r;
            *(f32x4*)(attn + (size_t)(i0 + r) * NPIX + jw + lane * 4) = v4;
        }
    }
    if (do_pv) {
#pragma unroll
        for (int st = 0; st < 8; ++st) {
#pragma unroll
            for (int ks = 0; ks < 8; ++ks) {
                bf16x8 af = *(const bf16x8*)(pbuf + (size_t)(st * 16 + li) * PROW +
                                             ks * 32 + lg * 8);   // P[i, j] unnorm
                const int j = st * 512 + ks * 32 + lg * 8;
                const unsigned short* vp0 = vb + (size_t)(wavei * 32 + li) * NPIX + j;
                o0 = mfma16(af, *(const bf16x8*)vp0, o0);
                o1 = mfma16(af, *(const bf16x8*)(vp0 + (size_t)16 * NPIX), o1);
            }
        }
        __syncthreads();               // everyone done READING half0
    } else {
        asm volatile("s_waitcnt lgkmcnt(0)" ::: "memory");  // own-region RAW fence
    }

    // rewrite own pbuf region with half1
#pragma unroll
    for (int s = 0; s < 16; ++s)
        *(uint32x2*)(prow + s * 16 + lg * 4) = sp2[s];
    if (do_pv) __syncthreads();        // half1 visible block-wide

    // ---- HALF 1: attn stores (b==0) + PV (gamma!=0) ----
    if (b == 0) {
        if (!do_pv) { asm volatile("s_waitcnt lgkmcnt(0)" ::: "memory"); }
#pragma unroll
        for (int r = 0; r < 16; ++r) {
            const float inv_r = __shfl(inv, r, 64);
            const unsigned short* rp = pbuf + (size_t)(wavei * 16 + r) * PROW;
            uint32x2 u = *(const uint32x2*)(rp + lane * 4);
            f32x4 v4;
            v4[0] = unpk_lo(u.x) * inv_r; v4[1] = unpk_hi(u.x) * inv_r;
            v4[2] = unpk_lo(u.y) * inv_r; v4[3] = unpk_hi(u.y) * inv_r;
            *(f32x4*)(attn + (size_t)(i0 + r) * NPIX + jw + 256 + lane * 4) = v4;
        }
    }
    if (do_pv) {
#pragma unroll
        for (int st = 0; st < 8; ++st) {
#pragma unroll
            for (int ks = 0; ks < 8; ++ks) {
                bf16x8 af = *(const bf16x8*)(pbuf + (size_t)(st * 16 + li) * PROW +
                                             ks * 32 + lg * 8);
                const int j = st * 512 + 256 + ks * 32 + lg * 8;
                const unsigned short* vp0 = vb + (size_t)(wavei * 32 + li) * NPIX + j;
                o0 = mfma16(af, *(const bf16x8*)vp0, o0);
                o1 = mfma16(af, *(const bf16x8*)(vp0 + (size_t)16 * NPIX), o1);
            }
        }
        // epilogue: out = gamma * (PV/l) + x
        // D2[i,c]: lane -> c = c0 + li, i = i0 + lg*4 + r
        const float* xbt = x + (size_t)b * C_ * NPIX;
        float* outb = out + (size_t)b * C_ * NPIX;
        f32x4 sc;
#pragma unroll
        for (int r = 0; r < 4; ++r) sc[r] = g * __shfl(inv, lg * 4 + r, 64);
        {
            int c = wavei * 32 + li;
            f32x4 xv = *(const f32x4*)(xbt + (size_t)c * NPIX + i0 + lg * 4);
            f32x4 r0 = o0 * sc + xv;
            *(f32x4*)(outb + (size_t)c * NPIX + i0 + lg * 4) = r0;
            c += 16;
            f32x4 xv1 = *(const f32x4*)(xbt + (size_t)c * NPIX + i0 + lg * 4);
            f32x4 r1 = o1 * sc + xv1;
            *(f32x4*)(outb + (size_t)c * NPIX + i0 + lg * 4) = r1;
        }
    }
}

extern "C" void kernel_launch(void* const* d_in, const int* in_sizes, int n_in,
                              void* d_out, int out_size, void* d_ws, size_t ws_size,
                              hipStream_t stream) {
    (void)in_sizes; (void)n_in; (void)out_size; (void)ws_size;
    const float* x     = (const float*)d_in[0];
    const float* Wq    = (const float*)d_in[1];
    const float* bq    = (const float*)d_in[2];
    const float* Wk    = (const float*)d_in[3];
    const float* bk    = (const float*)d_in[4];
    const float* Wv    = (const float*)d_in[5];
    const float* bv    = (const float*)d_in[6];
    const float* gamma = (const float*)d_in[7];

    float* out  = (float*)d_out;
    float* attn = out + OUT_ELEMS;

    unsigned short* qT = (unsigned short*)d_ws;                       // 1 MB
    unsigned short* kT = qT + (size_t)BATCH * NPIX * C8_;             // 1 MB
    unsigned short* vB = kT + (size_t)BATCH * NPIX * C8_;             // 8 MB (gamma!=0 only)

    k_proj<<<6144, 256, 0, stream>>>(x, Wq, bq, Wk, bk, Wv, bv, gamma,
                                     qT, kT, vB);

    k_attn5<<<1024, 512, 0, stream>>>(x, qT, kT, vB, gamma, out, attn);
}

// Round 13
// 33.092 us; speedup vs baseline: 1.7329x; 1.7329x over previous
//
#include <hip/hip_runtime.h>
#include <hip/hip_bf16.h>
#include <cstdint>
#include <cstddef>

// Problem dims (fixed by the reference: B=4, C=256, H=W=64)
#define C_    256
#define C8_   32
#define NPIX  4096
#define BATCH 4
#define OUT_ELEMS (BATCH * C_ * NPIX)   // out [4,256,64,64]; then attention [4096][4096]

typedef short bf16x8 __attribute__((ext_vector_type(8)));   // 8 bf16 in 4 VGPRs
typedef float f32x4  __attribute__((ext_vector_type(4)));
typedef unsigned uint32x2 __attribute__((ext_vector_type(2)));

#define LOG2E 1.44269504088896340736f

// k_attn4 LDS p-staging: per wave [16 rows][264 bf16] (HALF a j-range of 512;
// 256 data + 8 pad). 8*16*264*2B = 67.6 KB -> 2 blocks/CU.
#define PROW 264

static __device__ __forceinline__ unsigned short f2bf(float f) {
    union { float f; unsigned u; } v; v.f = f;
    unsigned r = v.u + 0x7fff + ((v.u >> 16) & 1);   // RNE
    return (unsigned short)(r >> 16);
}

// pack two f32 -> two bf16 (TRUNCATE) in one v_perm: low half = p0, high = p1
static __device__ __forceinline__ unsigned pack_bf2(float p0, float p1) {
    union { float f; unsigned u; } a, b; a.f = p0; b.f = p1;
    return __builtin_amdgcn_perm(b.u, a.u, 0x07060302u);
}
static __device__ __forceinline__ float unpk_lo(unsigned u) {
    union { unsigned u; float f; } v; v.u = u << 16; return v.f;
}
static __device__ __forceinline__ float unpk_hi(unsigned u) {
    union { unsigned u; float f; } v; v.u = u & 0xffff0000u; return v.f;
}

static __device__ __forceinline__ f32x4 mfma16(bf16x8 a, bf16x8 b, f32x4 c) {
    return __builtin_amdgcn_mfma_f32_16x16x32_bf16(a, b, c, 0, 0, 0);
}

// ---------------------------------------------------------------------------
// K1 "k_proj": [0,2048)    q/k projection (LDS-staged x, s_load W; R9-proven)
//              [2048,6144) v projection (skipped when gamma==0)
// gamma==0: only the 512 b==0 qk blocks do work; rest early-return.
//   qT,kT: bf16 [B][N][32] (c contiguous). q PRESCALED by log2(e).
//   vB   : bf16 [B][C][N]
// ---------------------------------------------------------------------------
__global__ __launch_bounds__(256) void k_proj(
    const float* __restrict__ x,
    const float* __restrict__ Wq, const float* __restrict__ bq,
    const float* __restrict__ Wk, const float* __restrict__ bk,
    const float* __restrict__ Wv, const float* __restrict__ bv,
    const float* __restrict__ gamma,
    unsigned short* __restrict__ qT,
    unsigned short* __restrict__ kT,
    unsigned short* __restrict__ vB)
{
    __shared__ float xs[256][64];     // 64 KB x-tile (qk role)
    __shared__ float pred[4][8][64];  // 8 KB cross-wave partials (qk role)

    const int bid = blockIdx.x;
    const float gval = gamma[0];

    if (bid < 2048) {                       // ---- q/k projection role ----
        const int idx = bid;
        const int b   = idx >> 9;           // 512 blocks per batch
        if (gval == 0.0f && b > 0) return;  // attention only observed at b==0
        const int sub  = idx & 511;
        const int og8  = sub >> 6;          // 0..7: 0-3 = q, 4-7 = k (uniform)
        const int n0   = (sub & 63) * 64;
        const bool is_q = (og8 < 4);
        const int obase = (og8 & 3) * 8;    // 8 outputs per block

        // stage x-tile [256 c][64 n]: 16 independent f32x4 loads per thread
        const int tl = threadIdx.x & 15;    // col group (4 floats)
        const int tr = threadIdx.x >> 4;    // row within pass (0..15)
        const float* xb = x + (size_t)b * C_ * NPIX + n0;
        f32x4 v[16];
#pragma unroll
        for (int p = 0; p < 16; ++p)
            v[p] = *(const f32x4*)(xb + (size_t)(p * 16 + tr) * NPIX + tl * 4);
#pragma unroll
        for (int p = 0; p < 16; ++p)
            *(f32x4*)&xs[p * 16 + tr][tl * 4] = v[p];
        __syncthreads();

        // each wave reduces its c-chunk of 64 for 8 outputs x 64 pixels
        const int wv = __builtin_amdgcn_readfirstlane(threadIdx.x >> 6); // 0..3
        const int ln = threadIdx.x & 63;    // pixel
        const float* Wb = (is_q ? Wq : Wk); // uniform (blockIdx-derived)
        float acc[8] = {0.f, 0.f, 0.f, 0.f, 0.f, 0.f, 0.f, 0.f};
#pragma unroll 8
        for (int cc = 0; cc < 64; ++cc) {
            const int c = wv * 64 + cc;     // wave-uniform -> W via s_load
            const float xv = xs[c][ln];
#pragma unroll
            for (int o = 0; o < 8; ++o)
                acc[o] = fmaf(Wb[(size_t)(obase + o) * C_ + c], xv, acc[o]);
        }
#pragma unroll
        for (int o = 0; o < 8; ++o) pred[wv][o][ln] = acc[o];
        __syncthreads();

        // reduce 4 partials + bias, convert, store (thread t -> 2 outputs)
        const int o1 = threadIdx.x >> 6;    // 0..3
        const int n  = threadIdx.x & 63;
#pragma unroll
        for (int k = 0; k < 2; ++k) {
            const int ol = o1 + k * 4;
            const int oa = obase + ol;
            float s = pred[0][ol][n] + pred[1][ol][n] +
                      pred[2][ol][n] + pred[3][ol][n];
            if (is_q) {
                s = (s + bq[oa]) * LOG2E;
                qT[((size_t)b * NPIX + n0 + n) * C8_ + oa] = f2bf(s);
            } else {
                s = s + bk[oa];
                kT[((size_t)b * NPIX + n0 + n) * C8_ + oa] = f2bf(s);
            }
        }
        return;
    }

    {                                       // ---- v projection role ----
        if (gval == 0.0f) return;
        const int idx = bid - 2048;
        const int b   = idx >> 10;          // 1024 blocks per batch
        const int rem = idx & 1023;
        const int w   = threadIdx.x >> 6;
        const int o0  = ((rem >> 6) * 4 + w) * 4;
        const int n   = (rem & 63) * 64 + (threadIdx.x & 63);

        float acc[4];
#pragma unroll
        for (int m = 0; m < 4; ++m) acc[m] = bv[o0 + m];
        const float* xb = x + (size_t)b * C_ * NPIX + n;
#pragma unroll 4
        for (int c = 0; c < C_; ++c) {
            float xv = xb[(size_t)c * NPIX];
#pragma unroll
            for (int m = 0; m < 4; ++m) acc[m] = fmaf(Wv[(o0 + m) * C_ + c], xv, acc[m]);
        }
#pragma unroll
        for (int m = 0; m < 4; ++m)
            vB[((size_t)b * C_ + o0 + m) * NPIX + n] = f2bf(acc[m]);
    }
}

// ---------------------------------------------------------------------------
// K2 "k_attn4": grid (256, 4) — R11 layout (x-fastest dispatch spreads the 256
// attention blocks round-robin across all 8 XCDs; R12's fid&3 interleave put
// them all on XCDs {0,4} -> 57 µs regression. Keep blocked roles.).
//  gamma==0: b==0 blocks -> attention; b>0 blocks -> out=x copy (overlapped).
//  gamma!=0: all blocks -> attention + per-half PV + out epilogue.
// R13 A/B: all stores PLAIN (was nontemporal in R11) — the only change.
// Two j-halves per wave: half0 in 68 KB pbuf, half1 in 32 VGPRs.
// Lane layout (m89-verified D): j = jw + s*16 + lg*4 + r, i = i0 + li.
// ---------------------------------------------------------------------------
__global__ __launch_bounds__(512, 4) void k_attn4(
    const float* __restrict__ x,
    const unsigned short* __restrict__ qT,
    const unsigned short* __restrict__ kT,
    const unsigned short* __restrict__ vB,
    const float* __restrict__ gamma,
    float* __restrict__ out,
    float* __restrict__ attn)
{
    const int b = blockIdx.y;
    const float g = gamma[0];

    __shared__ unsigned short pbuf[8 * 16 * PROW];   // 67.6 KB half-staging
    __shared__ float red[8][16];

    if (g == 0.0f && b > 0) {               // ---- copy role (768 blocks) ----
        const int cb = (b - 1) * 256 + blockIdx.x;   // 0..767
        const size_t n4 = (size_t)OUT_ELEMS / 4;     // 1,048,576 f32x4
        const f32x4* src = (const f32x4*)x;
        f32x4* dst = (f32x4*)out;
        for (size_t i = (size_t)cb * 512 + threadIdx.x; i < n4;
             i += (size_t)768 * 512)
            dst[i] = src[i];
        return;
    }

    const int i0   = blockIdx.x * 16;
    const int t    = threadIdx.x;
    const int lane = t & 63;
    const int wavei = __builtin_amdgcn_readfirstlane(t >> 6);  // 0..7
    const int li   = lane & 15;
    const int lg   = lane >> 4;       // 0..3

    const unsigned short* qTb = qT + (size_t)b * NPIX * C8_;
    const unsigned short* kTb = kT + (size_t)b * NPIX * C8_;

    // B fragment (Q, prescaled by log2e): rows i0+li, k-elems lg*8..+7
    bf16x8 qf = *(const bf16x8*)(qTb + (size_t)(i0 + li) * C8_ + lg * 8);

    const int jw = wavei * 512;
    unsigned short* prow = pbuf + (size_t)(wavei * 16 + li) * PROW;

    float ssum = 0.f;
    // HALF 0 (j local [0,256)): energy -> exp2 -> packed bf16 into pbuf
#pragma unroll
    for (int s = 0; s < 16; ++s) {
        bf16x8 kf = *(const bf16x8*)(kTb + (size_t)(jw + s * 16 + li) * C8_ + lg * 8);
        f32x4 z = {0.f, 0.f, 0.f, 0.f};
        f32x4 e = mfma16(kf, qf, z);           // e = S * log2e
        float p0 = exp2f(e[0]), p1 = exp2f(e[1]);
        float p2 = exp2f(e[2]), p3 = exp2f(e[3]);
        ssum += (p0 + p1) + (p2 + p3);
        uint32x2 pk;
        pk.x = pack_bf2(p0, p1);
        pk.y = pack_bf2(p2, p3);
        *(uint32x2*)(prow + s * 16 + lg * 4) = pk;   // 8B ds_write_b64
    }
    // HALF 1 (j local [256,512)): keep packed in registers (32 VGPR)
    uint32x2 sp2[16];
#pragma unroll
    for (int s = 0; s < 16; ++s) {
        bf16x8 kf = *(const bf16x8*)(kTb + (size_t)(jw + 256 + s * 16 + li) * C8_ + lg * 8);
        f32x4 z = {0.f, 0.f, 0.f, 0.f};
        f32x4 e = mfma16(kf, qf, z);
        float p0 = exp2f(e[0]), p1 = exp2f(e[1]);
        float p2 = exp2f(e[2]), p3 = exp2f(e[3]);
        ssum += (p0 + p1) + (p2 + p3);
        sp2[s].x = pack_bf2(p0, p1);
        sp2[s].y = pack_bf2(p2, p3);
    }

    // row sum: in-wave (across lg) then cross-wave via LDS
    ssum += __shfl_xor(ssum, 16, 64);
    ssum += __shfl_xor(ssum, 32, 64);
    if (lane < 16) red[wavei][lane] = ssum;
    __syncthreads();                   // pbuf half0 also visible block-wide
    float l = 0.f;
#pragma unroll
    for (int w = 0; w < 8; ++w) l += red[w][li];
    const float inv = 1.0f / l;        // row i0+li (lanes 0..15 canonical)

    const bool do_pv = (g != 0.0f);
    f32x4 o0 = {0.f, 0.f, 0.f, 0.f};
    f32x4 o1 = {0.f, 0.f, 0.f, 0.f};
    const unsigned short* vb = vB + (size_t)b * C_ * NPIX;

    // ---- HALF 0: attn stores (b==0) + PV (gamma!=0) ----
    if (b == 0) {
#pragma unroll
        for (int r = 0; r < 16; ++r) {
            const float inv_r = __shfl(inv, r, 64);
            const unsigned short* rp = pbuf + (size_t)(wavei * 16 + r) * PROW;
            uint32x2 u = *(const uint32x2*)(rp + lane * 4);   // 8B ds_read_b64
            f32x4 v4;
            v4[0] = unpk_lo(u.x) * inv_r; v4[1] = unpk_hi(u.x) * inv_r;
            v4[2] = unpk_lo(u.y) * inv_r; v4[3] = unpk_hi(u.y) * inv_r;
            *(f32x4*)(attn + (size_t)(i0 + r) * NPIX + jw + lane * 4) = v4;
        }
    }
    if (do_pv) {
#pragma unroll
        for (int st = 0; st < 8; ++st) {
#pragma unroll
            for (int ks = 0; ks < 8; ++ks) {
                bf16x8 af = *(const bf16x8*)(pbuf + (size_t)(st * 16 + li) * PROW +
                                             ks * 32 + lg * 8);   // P[i, j] unnorm
                const int j = st * 512 + ks * 32 + lg * 8;
                const unsigned short* vp0 = vb + (size_t)(wavei * 32 + li) * NPIX + j;
                o0 = mfma16(af, *(const bf16x8*)vp0, o0);
                o1 = mfma16(af, *(const bf16x8*)(vp0 + (size_t)16 * NPIX), o1);
            }
        }
        __syncthreads();               // everyone done READING half0
    } else {
        asm volatile("s_waitcnt lgkmcnt(0)" ::: "memory");  // own-region RAW fence
    }

    // rewrite own pbuf region with half1
#pragma unroll
    for (int s = 0; s < 16; ++s)
        *(uint32x2*)(prow + s * 16 + lg * 4) = sp2[s];
    if (do_pv) __syncthreads();        // half1 visible block-wide

    // ---- HALF 1: attn stores (b==0) + PV (gamma!=0) ----
    if (b == 0) {
        if (!do_pv) { asm volatile("s_waitcnt lgkmcnt(0)" ::: "memory"); }
#pragma unroll
        for (int r = 0; r < 16; ++r) {
            const float inv_r = __shfl(inv, r, 64);
            const unsigned short* rp = pbuf + (size_t)(wavei * 16 + r) * PROW;
            uint32x2 u = *(const uint32x2*)(rp + lane * 4);
            f32x4 v4;
            v4[0] = unpk_lo(u.x) * inv_r; v4[1] = unpk_hi(u.x) * inv_r;
            v4[2] = unpk_lo(u.y) * inv_r; v4[3] = unpk_hi(u.y) * inv_r;
            *(f32x4*)(attn + (size_t)(i0 + r) * NPIX + jw + 256 + lane * 4) = v4;
        }
    }
    if (do_pv) {
#pragma unroll
        for (int st = 0; st < 8; ++st) {
#pragma unroll
            for (int ks = 0; ks < 8; ++ks) {
                bf16x8 af = *(const bf16x8*)(pbuf + (size_t)(st * 16 + li) * PROW +
                                             ks * 32 + lg * 8);
                const int j = st * 512 + 256 + ks * 32 + lg * 8;
                const unsigned short* vp0 = vb + (size_t)(wavei * 32 + li) * NPIX + j;
                o0 = mfma16(af, *(const bf16x8*)vp0, o0);
                o1 = mfma16(af, *(const bf16x8*)(vp0 + (size_t)16 * NPIX), o1);
            }
        }
        // epilogue: out = gamma * (PV/l) + x
        // D2[i,c]: lane -> c = c0 + li, i = i0 + lg*4 + r
        const float* xbt = x + (size_t)b * C_ * NPIX;
        float* outb = out + (size_t)b * C_ * NPIX;
        f32x4 sc;
#pragma unroll
        for (int r = 0; r < 4; ++r) sc[r] = g * __shfl(inv, lg * 4 + r, 64);
        {
            int c = wavei * 32 + li;
            f32x4 xv = *(const f32x4*)(xbt + (size_t)c * NPIX + i0 + lg * 4);
            f32x4 r0 = o0 * sc + xv;
            *(f32x4*)(outb + (size_t)c * NPIX + i0 + lg * 4) = r0;
            c += 16;
            f32x4 xv1 = *(const f32x4*)(xbt + (size_t)c * NPIX + i0 + lg * 4);
            f32x4 r1 = o1 * sc + xv1;
            *(f32x4*)(outb + (size_t)c * NPIX + i0 + lg * 4) = r1;
        }
    }
}

extern "C" void kernel_launch(void* const* d_in, const int* in_sizes, int n_in,
                              void* d_out, int out_size, void* d_ws, size_t ws_size,
                              hipStream_t stream) {
    (void)in_sizes; (void)n_in; (void)out_size; (void)ws_size;
    const float* x     = (const float*)d_in[0];
    const float* Wq    = (const float*)d_in[1];
    const float* bq    = (const float*)d_in[2];
    const float* Wk    = (const float*)d_in[3];
    const float* bk    = (const float*)d_in[4];
    const float* Wv    = (const float*)d_in[5];
    const float* bv    = (const float*)d_in[6];
    const float* gamma = (const float*)d_in[7];

    float* out  = (float*)d_out;
    float* attn = out + OUT_ELEMS;

    unsigned short* qT = (unsigned short*)d_ws;                       // 1 MB
    unsigned short* kT = qT + (size_t)BATCH * NPIX * C8_;             // 1 MB
    unsigned short* vB = kT + (size_t)BATCH * NPIX * C8_;             // 8 MB (gamma!=0 only)

    k_proj<<<6144, 256, 0, stream>>>(x, Wq, bq, Wk, bk, Wv, bv, gamma,
                                     qT, kT, vB);

    dim3 g2(NPIX / 16, BATCH);
    k_attn4<<<g2, 512, 0, stream>>>(x, qT, kT, vB, gamma, out, attn);
}